// Round 12
// baseline (573.512 us; speedup 1.0000x reference)
//
#include <hip/hip_runtime.h>
#include <hip/hip_bf16.h>

// RoIAlign forward, torchvision semantics (aligned=false), fp32 in/out.
// N=2, C=256, H=200, W=200, K=1000 rois, pooled 7x7, sampling_ratio=2.
// Model (R1-R11): scattered-gather request-path bound at ~13 B/cy/CU; FETCH
// reductions (R10/R11) stopped moving dur. R12 decisive test: raise resident
// waves/CU 14 -> ~31 (256-thread blocks, NO LDS stage, 8 blocks/CU) to see
// if the per-CU miss-slot model scales. Costs 2x output write amplification
// (scattered 4B stores) - known from R1 to be ~+49MB HBM.
constexpr int Nn = 2, Cc = 256, Hh = 200, Ww = 200, Kk = 1000;
constexpr int PH = 7, PW = 7, SR = 2;
constexpr float SCALE = 0.25f;
constexpr int HWsz = Hh * Ww;
constexpr int NXCD = 8;
constexpr unsigned NUNITS = 2 * Kk;             // (roi, half) pairs
constexpr unsigned CHUNK = NUNITS / NXCD;       // 250

// ---------------------------------------------------------------------------
// NCHW fp32 -> NHWC bf16 (RTNE). 64x64 LDS tiles, coalesced both sides.
// ---------------------------------------------------------------------------
__global__ __launch_bounds__(256) void transpose_to_nhwc_bf16(
    const float* __restrict__ in, __hip_bfloat16* __restrict__ out) {
  __shared__ float tile[64][65];
  const int hw0 = blockIdx.x * 64;
  const int c0  = blockIdx.y * 64;
  const int b   = blockIdx.z;
  const int lane = threadIdx.x & 63;
  const int row  = threadIdx.x >> 6;  // 0..3

#pragma unroll
  for (int i = 0; i < 16; ++i) {
    const int cc = row + i * 4;
    tile[cc][lane] = in[(size_t)(b * Cc + c0 + cc) * HWsz + hw0 + lane];
  }
  __syncthreads();
#pragma unroll
  for (int i = 0; i < 16; ++i) {
    const int hh = row + i * 4;
    out[((size_t)b * HWsz + hw0 + hh) * Cc + c0 + lane] =
        __float2bfloat16(tile[lane][hh]);
  }
}

// ---------------------------------------------------------------------------
// Morton-order counting sort of rois by (batch, morton(yc/8, xc/8)).
// 2048 buckets; single-pass (K=1000 <= 1024 threads); Hillis-Steele scan.
// Per-roi output location is fixed by roi index -> intra-bucket order
// nondeterminism is harmless.
// ---------------------------------------------------------------------------
__global__ __launch_bounds__(1024) void sort_rois(
    const float* __restrict__ rois, unsigned* __restrict__ order) {
  __shared__ unsigned A[2048], B[2048];
  const int tid = (int)threadIdx.x;
  A[tid] = 0; A[tid + 1024] = 0;
  __syncthreads();

  unsigned kk = 0;
  const bool act = tid < Kk;
  if (act) {
    const float* r = rois + tid * 5;
    int yc = (int)(0.5f * (r[2] + r[4]) * SCALE);
    int xc = (int)(0.5f * (r[1] + r[3]) * SCALE);
    yc = yc < 0 ? 0 : (yc > 199 ? 199 : yc);
    xc = xc < 0 ? 0 : (xc > 199 ? 199 : xc);
    const unsigned ty = (unsigned)yc >> 3, tx = (unsigned)xc >> 3;  // 0..24
    unsigned m = 0;
#pragma unroll
    for (int i = 0; i < 5; ++i)
      m |= (((ty >> i) & 1u) << (2 * i + 1)) | (((tx >> i) & 1u) << (2 * i));
    kk = (unsigned)r[0] * 1024u + m;
    atomicAdd(&A[kk], 1u);
  }
  __syncthreads();

  unsigned* src = A;
  unsigned* dst = B;
  for (int d = 1; d < 2048; d <<= 1) {
    for (int j = tid; j < 2048; j += 1024) {
      unsigned v = src[j];
      if (j >= d) v += src[j - d];
      dst[j] = v;
    }
    __syncthreads();
    unsigned* t = src; src = dst; dst = t;
  }
  for (int j = tid; j < 2048; j += 1024) dst[j] = j ? src[j - 1] : 0u;
  __syncthreads();

  if (act) {
    const unsigned pos = atomicAdd(&dst[kk], 1u);
    order[pos] = (unsigned)tid;
  }
}

// ---------------------------------------------------------------------------
// RoI align on NHWC bf16, XCD-chunked over Morton-sorted units, NO LDS.
// Block = 256 threads (4 waves), unit = (roi = order[u>>1], half = u&1).
// Wave w handles bins p in [ceil(49w/4), ceil(49(w+1)/4)) (13/12/12/12).
// Lane: ixl = lane>>5 (x-sample column), cq = lane&31 (channel quad of the
// 128-ch half; ushort4 = 8B loads -> 2x256B coalesced segments per gather).
// Output written directly (scattered dwords, ~2x write amp) - no LDS so up
// to 8 blocks/CU resident.
// ---------------------------------------------------------------------------
__global__ __launch_bounds__(256, 8) void roi_align_hiocc(
    const ushort* __restrict__ feat, const float* __restrict__ rois,
    const unsigned* __restrict__ order, float* __restrict__ out) {
  const unsigned bid = blockIdx.x;
  const unsigned unit = (bid % NXCD) * CHUNK + bid / NXCD;

  const int tid  = (int)threadIdx.x;
  const int w    = tid >> 6;        // wave 0..3
  const int lane = tid & 63;
  const int ixl  = lane >> 5;       // sample column parity
  const int cq   = lane & 31;       // channel quad in half

  const int k    = (int)order[unit >> 1];
  const int half = (int)(unit & 1);

  const float* r = rois + k * 5;
  const int b = (int)r[0];
  const float x1 = r[1] * SCALE;
  const float y1 = r[2] * SCALE;
  const float x2 = r[3] * SCALE;
  const float y2 = r[4] * SCALE;
  const float bin_w = fmaxf(x2 - x1, 1.0f) * (1.0f / PW);
  const float bin_h = fmaxf(y2 - y1, 1.0f) * (1.0f / PH);

  // ushort4 view; per-(y,x) stride is 64 quads; this lane's channel quad.
  const ushort4* fb =
      (const ushort4*)(feat + (size_t)b * HWsz * Cc) + half * 32 + cq;

  auto bf2f = [](ushort u) -> float {
    return __uint_as_float((unsigned)u << 16);
  };
  const float x_off = ((float)ixl + 0.5f) * 0.5f;  // per-lane sample offset

  // This lane's 4-channel output base: out[k][half*128 + cq*4 + j][p].
  float* ob = out + (size_t)k * (Cc * PH * PW) + (half * 128 + cq * 4) * 49;

  const int p0 = (49 * w + 3) >> 2;        // {0,13,25,37}
  const int p1 = (49 * (w + 1) + 3) >> 2;  // {13,25,37,49}

  for (int p = p0; p < p1; ++p) {
    const int ph = p / 7;
    const int pw = p - ph * 7;

    // x setup (per-lane sample column).
    const float x  = x1 + ((float)pw + x_off) * bin_w;
    const bool vx  = (x >= -1.0f) && (x <= (float)Ww);
    const float cx = fmaxf(x, 0.0f);
    int xl = (int)cx;
    int xh;
    float fx;
    if (xl >= Ww - 1) { xl = Ww - 1; xh = Ww - 1; fx = 0.0f; }
    else              { xh = xl + 1; fx = cx - (float)xl; }
    float wxl = 1.0f - fx, wxh = fx;
    if (!vx) { wxl = 0.0f; wxh = 0.0f; }

    float4 a = make_float4(0.f, 0.f, 0.f, 0.f);

#pragma unroll
    for (int iy = 0; iy < SR; ++iy) {
      const float y  = y1 + ((float)ph + ((float)iy + 0.5f) * 0.5f) * bin_h;
      const bool vy  = (y >= -1.0f) && (y <= (float)Hh);
      const float cy = fmaxf(y, 0.0f);
      int yl = (int)cy;  // cy >= 0: trunc == floor
      int yh;
      float fy;
      if (yl >= Hh - 1) { yl = Hh - 1; yh = Hh - 1; fy = 0.0f; }
      else              { yh = yl + 1; fy = cy - (float)yl; }
      float wyl = 1.0f - fy, wyh = fy;
      if (!vy) { wyl = 0.0f; wyh = 0.0f; }

      const float w00 = wyl * wxl, w01 = wyl * wxh;
      const float w10 = wyh * wxl, w11 = wyh * wxh;

      const ushort4 v00 = fb[(yl * Ww + xl) * 64];
      const ushort4 v01 = fb[(yl * Ww + xh) * 64];
      const ushort4 v10 = fb[(yh * Ww + xl) * 64];
      const ushort4 v11 = fb[(yh * Ww + xh) * 64];

      a.x = fmaf(w00, bf2f(v00.x), fmaf(w01, bf2f(v01.x),
            fmaf(w10, bf2f(v10.x), fmaf(w11, bf2f(v11.x), a.x))));
      a.y = fmaf(w00, bf2f(v00.y), fmaf(w01, bf2f(v01.y),
            fmaf(w10, bf2f(v10.y), fmaf(w11, bf2f(v11.y), a.y))));
      a.z = fmaf(w00, bf2f(v00.z), fmaf(w01, bf2f(v01.z),
            fmaf(w10, bf2f(v10.z), fmaf(w11, bf2f(v11.z), a.z))));
      a.w = fmaf(w00, bf2f(v00.w), fmaf(w01, bf2f(v01.w),
            fmaf(w10, bf2f(v10.w), fmaf(w11, bf2f(v11.w), a.w))));
    }

    // Fold the two x-sample columns: lane L <-> lane L^32.
    a.x += __shfl_xor(a.x, 32);
    a.y += __shfl_xor(a.y, 32);
    a.z += __shfl_xor(a.z, 32);
    a.w += __shfl_xor(a.w, 32);

    if (lane < 32) {
      const float inv = 1.0f / (SR * SR);
      __builtin_nontemporal_store(a.x * inv, &ob[0 * 49 + p]);
      __builtin_nontemporal_store(a.y * inv, &ob[1 * 49 + p]);
      __builtin_nontemporal_store(a.z * inv, &ob[2 * 49 + p]);
      __builtin_nontemporal_store(a.w * inv, &ob[3 * 49 + p]);
    }
  }
}

extern "C" void kernel_launch(void* const* d_in, const int* in_sizes, int n_in,
                              void* d_out, int out_size, void* d_ws, size_t ws_size,
                              hipStream_t stream) {
  const float* inp  = (const float*)d_in[0];   // (2,256,200,200) fp32
  const float* rois = (const float*)d_in[1];   // (1000,5) fp32
  float* out = (float*)d_out;                  // (1000,256,7,7) fp32

  __hip_bfloat16* nhwc = (__hip_bfloat16*)d_ws;                // 41 MB
  unsigned* order = (unsigned*)((char*)d_ws + (48u << 20));    // 4KB @48MB

  transpose_to_nhwc_bf16<<<dim3(HWsz / 64, Cc / 64, Nn), 256, 0, stream>>>(inp, nhwc);
  sort_rois<<<dim3(1), 1024, 0, stream>>>(rois, order);
  roi_align_hiocc<<<dim3(NUNITS), 256, 0, stream>>>((const ushort*)nhwc, rois, order, out);
}

// Round 13
// 62.685 us; speedup vs baseline: 9.1491x; 9.1491x over previous
//
#include <hip/hip_runtime.h>
#include <hip/hip_bf16.h>

// RoIAlign forward, torchvision semantics (aligned=false), fp32 in/out.
// N=2, C=256, H=200, W=200, K=1000 rois, pooled 7x7, sampling_ratio=2.
// Model (R1-R12): scattered-gather request-path bound; FETCH reductions
// stopped moving dur (R11); NT scattered stores are catastrophic (R12).
// R13: R11's structure with 256-thread/4-wave blocks (LDS 26.8KB -> 5
// blocks/CU, ~20 waves/CU vs R11's 14) to test wave-concurrency scaling
// with the write path identical to R11 (coalesced NT stage-out).
constexpr int Nn = 2, Cc = 256, Hh = 200, Ww = 200, Kk = 1000;
constexpr int PH = 7, PW = 7, SR = 2;
constexpr float SCALE = 0.25f;
constexpr int HWsz = Hh * Ww;
constexpr int NXCD = 8;
constexpr unsigned NUNITS = 2 * Kk;             // (roi, half) pairs
constexpr unsigned CHUNK = NUNITS / NXCD;       // 250

// ---------------------------------------------------------------------------
// NCHW fp32 -> NHWC bf16 (RTNE). 64x64 LDS tiles, coalesced both sides.
// ---------------------------------------------------------------------------
__global__ __launch_bounds__(256) void transpose_to_nhwc_bf16(
    const float* __restrict__ in, __hip_bfloat16* __restrict__ out) {
  __shared__ float tile[64][65];
  const int hw0 = blockIdx.x * 64;
  const int c0  = blockIdx.y * 64;
  const int b   = blockIdx.z;
  const int lane = threadIdx.x & 63;
  const int row  = threadIdx.x >> 6;  // 0..3

#pragma unroll
  for (int i = 0; i < 16; ++i) {
    const int cc = row + i * 4;
    tile[cc][lane] = in[(size_t)(b * Cc + c0 + cc) * HWsz + hw0 + lane];
  }
  __syncthreads();
#pragma unroll
  for (int i = 0; i < 16; ++i) {
    const int hh = row + i * 4;
    out[((size_t)b * HWsz + hw0 + hh) * Cc + c0 + lane] =
        __float2bfloat16(tile[lane][hh]);
  }
}

// ---------------------------------------------------------------------------
// Morton-order counting sort of rois by (batch, morton(yc/8, xc/8)).
// 2048 buckets; single-pass (K=1000 <= 1024 threads); Hillis-Steele scan.
// Per-roi output location is fixed by roi index -> intra-bucket order
// nondeterminism is harmless.
// ---------------------------------------------------------------------------
__global__ __launch_bounds__(1024) void sort_rois(
    const float* __restrict__ rois, unsigned* __restrict__ order) {
  __shared__ unsigned A[2048], B[2048];
  const int tid = (int)threadIdx.x;
  A[tid] = 0; A[tid + 1024] = 0;
  __syncthreads();

  unsigned kk = 0;
  const bool act = tid < Kk;
  if (act) {
    const float* r = rois + tid * 5;
    int yc = (int)(0.5f * (r[2] + r[4]) * SCALE);
    int xc = (int)(0.5f * (r[1] + r[3]) * SCALE);
    yc = yc < 0 ? 0 : (yc > 199 ? 199 : yc);
    xc = xc < 0 ? 0 : (xc > 199 ? 199 : xc);
    const unsigned ty = (unsigned)yc >> 3, tx = (unsigned)xc >> 3;  // 0..24
    unsigned m = 0;
#pragma unroll
    for (int i = 0; i < 5; ++i)
      m |= (((ty >> i) & 1u) << (2 * i + 1)) | (((tx >> i) & 1u) << (2 * i));
    kk = (unsigned)r[0] * 1024u + m;
    atomicAdd(&A[kk], 1u);
  }
  __syncthreads();

  unsigned* src = A;
  unsigned* dst = B;
  for (int d = 1; d < 2048; d <<= 1) {
    for (int j = tid; j < 2048; j += 1024) {
      unsigned v = src[j];
      if (j >= d) v += src[j - d];
      dst[j] = v;
    }
    __syncthreads();
    unsigned* t = src; src = dst; dst = t;
  }
  for (int j = tid; j < 2048; j += 1024) dst[j] = j ? src[j - 1] : 0u;
  __syncthreads();

  if (act) {
    const unsigned pos = atomicAdd(&dst[kk], 1u);
    order[pos] = (unsigned)tid;
  }
}

// Skewed LDS index: writer lanes land on bank stride 17 (coprime with 32)
// -> conflict-free writes; reads quasi-linear.
__device__ __forceinline__ int sidx(int c, int p) {
  return c * 49 + p + 13 * (c >> 2);
}

// ---------------------------------------------------------------------------
// RoI align on NHWC bf16, XCD-chunked over Morton-sorted units.
// Block = 256 threads (4 waves); unit -> (roi = order[u>>1], half = u&1).
// Wave w handles bins p in [ceil(49w/4), ceil(49(w+1)/4)) (13/12/12/12).
// Lane: ixl = lane>>5 (x-sample column), cq = lane&31 (channel quad of the
// 128-ch half; ushort4 = 8B loads -> 2x256B coalesced segments per gather).
// Results staged per-bin into skewed LDS; one barrier; coalesced NT
// write-out (full-line dirtying -> no write amplification, per R4-R11).
// ---------------------------------------------------------------------------
__global__ __launch_bounds__(256, 5) void roi_align_hiocc(
    const ushort* __restrict__ feat, const float* __restrict__ rois,
    const unsigned* __restrict__ order, float* __restrict__ out) {
  __shared__ float stage[6704];  // 128ch x 49, skewed (max idx 6674)

  const unsigned bid = blockIdx.x;
  const unsigned unit = (bid % NXCD) * CHUNK + bid / NXCD;

  const int tid  = (int)threadIdx.x;
  const int w    = tid >> 6;        // wave 0..3
  const int lane = tid & 63;
  const int ixl  = lane >> 5;       // sample column parity
  const int cq   = lane & 31;       // channel quad in half

  const int k    = (int)order[unit >> 1];
  const int half = (int)(unit & 1);

  const float* r = rois + k * 5;
  const int b = (int)r[0];
  const float x1 = r[1] * SCALE;
  const float y1 = r[2] * SCALE;
  const float x2 = r[3] * SCALE;
  const float y2 = r[4] * SCALE;
  const float bin_w = fmaxf(x2 - x1, 1.0f) * (1.0f / PW);
  const float bin_h = fmaxf(y2 - y1, 1.0f) * (1.0f / PH);

  // ushort4 view; per-(y,x) stride is 64 quads; this lane's channel quad.
  const ushort4* fb =
      (const ushort4*)(feat + (size_t)b * HWsz * Cc) + half * 32 + cq;

  auto bf2f = [](ushort u) -> float {
    return __uint_as_float((unsigned)u << 16);
  };
  const float x_off = ((float)ixl + 0.5f) * 0.5f;  // per-lane sample offset
  const float inv = 1.0f / (SR * SR);

  const int p0 = (49 * w + 3) >> 2;        // {0,13,25,37}
  const int p1 = (49 * (w + 1) + 3) >> 2;  // {13,25,37,49}

  for (int p = p0; p < p1; ++p) {
    const int ph = p / 7;
    const int pw = p - ph * 7;

    // x setup (per-lane sample column).
    const float x  = x1 + ((float)pw + x_off) * bin_w;
    const bool vx  = (x >= -1.0f) && (x <= (float)Ww);
    const float cx = fmaxf(x, 0.0f);
    int xl = (int)cx;
    int xh;
    float fx;
    if (xl >= Ww - 1) { xl = Ww - 1; xh = Ww - 1; fx = 0.0f; }
    else              { xh = xl + 1; fx = cx - (float)xl; }
    float wxl = 1.0f - fx, wxh = fx;
    if (!vx) { wxl = 0.0f; wxh = 0.0f; }

    float4 a = make_float4(0.f, 0.f, 0.f, 0.f);

#pragma unroll
    for (int iy = 0; iy < SR; ++iy) {
      const float y  = y1 + ((float)ph + ((float)iy + 0.5f) * 0.5f) * bin_h;
      const bool vy  = (y >= -1.0f) && (y <= (float)Hh);
      const float cy = fmaxf(y, 0.0f);
      int yl = (int)cy;  // cy >= 0: trunc == floor
      int yh;
      float fy;
      if (yl >= Hh - 1) { yl = Hh - 1; yh = Hh - 1; fy = 0.0f; }
      else              { yh = yl + 1; fy = cy - (float)yl; }
      float wyl = 1.0f - fy, wyh = fy;
      if (!vy) { wyl = 0.0f; wyh = 0.0f; }

      const float w00 = wyl * wxl, w01 = wyl * wxh;
      const float w10 = wyh * wxl, w11 = wyh * wxh;

      const ushort4 v00 = fb[(yl * Ww + xl) * 64];
      const ushort4 v01 = fb[(yl * Ww + xh) * 64];
      const ushort4 v10 = fb[(yh * Ww + xl) * 64];
      const ushort4 v11 = fb[(yh * Ww + xh) * 64];

      a.x = fmaf(w00, bf2f(v00.x), fmaf(w01, bf2f(v01.x),
            fmaf(w10, bf2f(v10.x), fmaf(w11, bf2f(v11.x), a.x))));
      a.y = fmaf(w00, bf2f(v00.y), fmaf(w01, bf2f(v01.y),
            fmaf(w10, bf2f(v10.y), fmaf(w11, bf2f(v11.y), a.y))));
      a.z = fmaf(w00, bf2f(v00.z), fmaf(w01, bf2f(v01.z),
            fmaf(w10, bf2f(v10.z), fmaf(w11, bf2f(v11.z), a.z))));
      a.w = fmaf(w00, bf2f(v00.w), fmaf(w01, bf2f(v01.w),
            fmaf(w10, bf2f(v10.w), fmaf(w11, bf2f(v11.w), a.w))));
    }

    // Fold the two x-sample columns: lane L <-> lane L^32.
    a.x += __shfl_xor(a.x, 32);
    a.y += __shfl_xor(a.y, 32);
    a.z += __shfl_xor(a.z, 32);
    a.w += __shfl_xor(a.w, 32);

    if (lane < 32) {
      const int c0 = cq * 4;
      stage[sidx(c0 + 0, p)] = a.x * inv;
      stage[sidx(c0 + 1, p)] = a.y * inv;
      stage[sidx(c0 + 2, p)] = a.z * inv;
      stage[sidx(c0 + 3, p)] = a.w * inv;
    }
  }
  __syncthreads();  // stage complete (each wave wrote its own bins)

  const size_t obase =
      (size_t)k * (Cc * PH * PW) + (size_t)half * (128 * PH * PW);
  // 128*49 = 6272 floats = 24.5 x 256 threads.
#pragma unroll
  for (int i = 0; i < 24; ++i) {
    const int idx = i * 256 + tid;
    const int c = idx / 49, p = idx - c * 49;
    // NT on COALESCED stores only (full-line dirtying) - R12 lesson.
    __builtin_nontemporal_store(stage[sidx(c, p)], &out[obase + idx]);
  }
  {
    const int idx = 24 * 256 + tid;
    if (idx < 6272) {
      const int c = idx / 49, p = idx - c * 49;
      __builtin_nontemporal_store(stage[sidx(c, p)], &out[obase + idx]);
    }
  }
}

extern "C" void kernel_launch(void* const* d_in, const int* in_sizes, int n_in,
                              void* d_out, int out_size, void* d_ws, size_t ws_size,
                              hipStream_t stream) {
  const float* inp  = (const float*)d_in[0];   // (2,256,200,200) fp32
  const float* rois = (const float*)d_in[1];   // (1000,5) fp32
  float* out = (float*)d_out;                  // (1000,256,7,7) fp32

  __hip_bfloat16* nhwc = (__hip_bfloat16*)d_ws;                // 41 MB
  unsigned* order = (unsigned*)((char*)d_ws + (48u << 20));    // 4KB @48MB

  transpose_to_nhwc_bf16<<<dim3(HWsz / 64, Cc / 64, Nn), 256, 0, stream>>>(inp, nhwc);
  sort_rois<<<dim3(1), 1024, 0, stream>>>(rois, order);
  roi_align_hiocc<<<dim3(NUNITS), 256, 0, stream>>>((const ushort*)nhwc, rois, order, out);
}